// Round 9
// baseline (209.826 us; speedup 1.0000x reference)
//
#include <hip/hip_runtime.h>
#include <hip/hip_bf16.h>
#include <math.h>

#define N_TOK 4096
#define M_TOK 1024
#define DMODEL 512
#define NHEAD 8
#define DHEAD 64
#define NBLK 512

typedef __attribute__((ext_vector_type(8))) short short8;
typedef __attribute__((ext_vector_type(4))) float f32x4;
typedef __attribute__((ext_vector_type(4))) float float4v;

static __device__ __forceinline__ short f2bf(float f) {
    union { float f; unsigned u; } v; v.f = f;
    unsigned r = v.u + 0x7fffu + ((v.u >> 16) & 1u);
    return (short)(r >> 16);
}

#define GLOAD_LDS16(g, l) __builtin_amdgcn_global_load_lds( \
    (const __attribute__((address_space(1))) void*)(g), \
    (__attribute__((address_space(3))) void*)(l), 16, 0, 0)

struct SMemG { short As[64][72]; short Bs[64][72]; };
struct SMemA { short Ks[2][64][64]; short Vs[2][64][64]; short Ps[4][16][72]; };
union SMemU { SMemG g; SMemA a; };

// ---------------------------------------------------------------------------
// Device-scope grid barrier (all NBLK blocks co-resident by construction:
// 42.6 KB LDS -> 3 blocks/CU capacity > 512-block grid; regular launch, so
// graph capture is unaffected). Generation-based, reusable.
// ---------------------------------------------------------------------------
static __device__ __forceinline__ void gridbar(unsigned* cnt, unsigned* gen) {
    __syncthreads();
    if (threadIdx.x == 0) {
        __threadfence();
        unsigned g = __hip_atomic_load(gen, __ATOMIC_RELAXED, __HIP_MEMORY_SCOPE_AGENT);
        if (__hip_atomic_fetch_add(cnt, 1u, __ATOMIC_ACQ_REL, __HIP_MEMORY_SCOPE_AGENT) == NBLK - 1u) {
            __hip_atomic_store(cnt, 0u, __ATOMIC_RELAXED, __HIP_MEMORY_SCOPE_AGENT);
            __hip_atomic_store(gen, g + 1u, __ATOMIC_RELEASE, __HIP_MEMORY_SCOPE_AGENT);
        } else {
            unsigned cur;
            do {
                __builtin_amdgcn_s_sleep(2);
                cur = __hip_atomic_load(gen, __ATOMIC_ACQUIRE, __HIP_MEMORY_SCOPE_AGENT);
            } while (cur == g);
        }
    }
    __syncthreads();
}

// ---------------------------------------------------------------------------
// Pack: fp32 -> bf16 (weights TRANSPOSED B^T[n][k]); zeroes barrier words.
// ---------------------------------------------------------------------------
__global__ void pack_kernel(const float* __restrict__ xv, const float* __restrict__ xt,
                            const float* __restrict__ wq, const float* __restrict__ wk,
                            const float* __restrict__ wv, const float* __restrict__ wo,
                            short* __restrict__ xvb, short* __restrict__ xtb,
                            short* __restrict__ wqb, short* __restrict__ wkb,
                            short* __restrict__ wvb, short* __restrict__ wob,
                            unsigned* __restrict__ bar) {
    int idx = blockIdx.x * 256 + threadIdx.x;
    int stride = gridDim.x * 256;
    if (idx == 0) { bar[0] = 0u; bar[1] = 0u; }
    const int CXV = N_TOK * DMODEL / 8;
    const int CXT = M_TOK * DMODEL / 8;
    const int NW  = DMODEL * DMODEL;
    for (int c = idx; c < CXV; c += stride) {
        float4v f0 = *(const float4v*)&xv[c * 8];
        float4v f1 = *(const float4v*)&xv[c * 8 + 4];
        short8 o;
        #pragma unroll
        for (int j = 0; j < 4; j++) { o[j] = f2bf(f0[j]); o[j + 4] = f2bf(f1[j]); }
        *(short8*)&xvb[c * 8] = o;
    }
    for (int c = idx; c < CXT; c += stride) {
        float4v f0 = *(const float4v*)&xt[c * 8];
        float4v f1 = *(const float4v*)&xt[c * 8 + 4];
        short8 o;
        #pragma unroll
        for (int j = 0; j < 4; j++) { o[j] = f2bf(f0[j]); o[j + 4] = f2bf(f1[j]); }
        *(short8*)&xtb[c * 8] = o;
    }
    for (int i = idx; i < NW; i += stride) {
        int n = i >> 9;
        int k = i & 511;
        int h = n >> 6, e = n & 63;
        int src = h * (DMODEL * DHEAD) + k * DHEAD + e;
        wqb[i] = f2bf(wq[src]);
        wkb[i] = f2bf(wk[src]);
        wvb[i] = f2bf(wv[src]);
        wob[i] = f2bf(wo[k * DMODEL + n]);
    }
}

// ---------------------------------------------------------------------------
// GEMM tile body (r5/r8-proven): 64x64, BK=64, padded LDS, reg-staging with
// next-step loads issued right after the barrier. Wave (wr,wc) = 32x32 quad.
// ---------------------------------------------------------------------------
template<typename EPI>
static __device__ __forceinline__ void gemm_body(SMemG& sm,
                                                 const short* __restrict__ A,
                                                 const short* __restrict__ BT,
                                                 int m0, int n0, EPI epi) {
    int t = threadIdx.x;
    int lane = t & 63, w = t >> 6;
    int wr = w >> 1, wc = w & 1;
    int l15 = lane & 15, g = lane >> 4;

    int row = t >> 2, c0 = (t & 3) * 16;
    const short* gA = A + (size_t)(m0 + row) * DMODEL + c0;
    const short* gB = BT + (size_t)(n0 + row) * DMODEL + c0;

    short8 ra0 = *(const short8*)gA;
    short8 ra1 = *(const short8*)(gA + 8);
    short8 rb0 = *(const short8*)gB;
    short8 rb1 = *(const short8*)(gB + 8);

    f32x4 acc[2][2] = {};
    #pragma unroll
    for (int step = 0; step < DMODEL / 64; ++step) {
        *(short8*)&sm.As[row][c0]     = ra0;
        *(short8*)&sm.As[row][c0 + 8] = ra1;
        *(short8*)&sm.Bs[row][c0]     = rb0;
        *(short8*)&sm.Bs[row][c0 + 8] = rb1;
        __syncthreads();
        if (step < DMODEL / 64 - 1) {
            gA += 64; gB += 64;
            ra0 = *(const short8*)gA;
            ra1 = *(const short8*)(gA + 8);
            rb0 = *(const short8*)gB;
            rb1 = *(const short8*)(gB + 8);
        }
        #pragma unroll
        for (int ks = 0; ks < 2; ks++) {
            short8 a[2], b[2];
            #pragma unroll
            for (int fr = 0; fr < 2; fr++) a[fr] = *(short8*)&sm.As[wr * 32 + fr * 16 + l15][ks * 32 + g * 8];
            #pragma unroll
            for (int fc = 0; fc < 2; fc++) b[fc] = *(short8*)&sm.Bs[wc * 32 + fc * 16 + l15][ks * 32 + g * 8];
            #pragma unroll
            for (int fr = 0; fr < 2; fr++)
                #pragma unroll
                for (int fc = 0; fc < 2; fc++)
                    acc[fr][fc] = __builtin_amdgcn_mfma_f32_16x16x32_bf16(a[fr], b[fc], acc[fr][fc], 0, 0, 0);
        }
        __syncthreads();
    }
    #pragma unroll
    for (int fr = 0; fr < 2; fr++)
        #pragma unroll
        for (int fc = 0; fc < 2; fc++)
            #pragma unroll
            for (int r = 0; r < 4; r++) {
                int orow = m0 + wr * 32 + fr * 16 + g * 4 + r;
                int ocol = n0 + wc * 32 + fc * 16 + l15;
                epi(orow, ocol, acc[fr][fc][r]);
            }
}

// one QKV tile by flat index: [0,512) Q, [512,640) K, [640,768) V
static __device__ __forceinline__ void qkv_tile(SMemG& sm, int tile,
                                                const short* xvb, const short* xtb,
                                                const short* wqb, const short* wkb,
                                                const short* wvb,
                                                short* qb, short* kbm, short* vbt) {
    if (tile < 512) {
        gemm_body(sm, xvb, wqb, (tile >> 3) * 64, (tile & 7) * 64,
                  [&](int row, int col, float v) { qb[(size_t)row * DMODEL + col] = f2bf(v); });
    } else if (tile < 640) {
        int b = tile - 512;
        gemm_body(sm, xtb, wkb, (b >> 3) * 64, (b & 7) * 64,
                  [&](int row, int col, float v) { kbm[(size_t)row * DMODEL + col] = f2bf(v); });
    } else {
        int b = tile - 640;
        gemm_body(sm, xtb, wvb, (b >> 3) * 64, (b & 7) * 64,
                  [&](int row, int col, float v) { vbt[(size_t)col * M_TOK + row] = f2bf(v); });
    }
}

// ---------------------------------------------------------------------------
// Attention tile (r5-proven v5): LDS-staged, double-buffered, XOR-swizzled.
// ---------------------------------------------------------------------------
static __device__ __forceinline__ void attn_tile(SMemA& sm, int bid,
                                                 const short* __restrict__ Qb,
                                                 const short* __restrict__ Kb,
                                                 const short* __restrict__ VbT,
                                                 short* __restrict__ Yb) {
    int h = bid & 7;
    int n0 = (bid >> 3) * 64;
    int t = threadIdx.x;
    int lane = t & 63, w = t >> 6;
    int l15 = lane & 15, g = lane >> 4;

    const short* Kh  = Kb + h * DHEAD;
    const short* VhT = VbT + (h * DHEAD) * M_TOK;

    int srow = (lane >> 3);
    int sgran = (lane & 7) ^ srow;
    const short* gK0 = Kh + (size_t)(w * 16 + srow) * DMODEL + sgran * 8;
    const short* gV0 = VhT + (size_t)(w * 16 + srow) * M_TOK + sgran * 8;

    const short* qrow = Qb + (size_t)(n0 + w * 16 + l15) * DMODEL + h * DHEAD;
    short8 qa0 = *(const short8*)(qrow + g * 8);
    short8 qa1 = *(const short8*)(qrow + 32 + g * 8);

    f32x4 acc[4] = {};
    f32x4 rsum = {};
    int sx = l15 & 7;

    GLOAD_LDS16(gK0,              &sm.Ks[0][w * 16][0]);
    GLOAD_LDS16(gK0 + 8 * DMODEL, &sm.Ks[0][w * 16 + 8][0]);
    GLOAD_LDS16(gV0,              &sm.Vs[0][w * 16][0]);
    GLOAD_LDS16(gV0 + 8 * M_TOK,  &sm.Vs[0][w * 16 + 8][0]);
    __syncthreads();

    int buf = 0;
    for (int it = 0; it < 16; ++it) {
        if (it < 15) {
            int key0 = (it + 1) * 64;
            GLOAD_LDS16(gK0 + (size_t)key0 * DMODEL,       &sm.Ks[buf ^ 1][w * 16][0]);
            GLOAD_LDS16(gK0 + (size_t)(key0 + 8) * DMODEL, &sm.Ks[buf ^ 1][w * 16 + 8][0]);
            GLOAD_LDS16(gV0 + key0,                        &sm.Vs[buf ^ 1][w * 16][0]);
            GLOAD_LDS16(gV0 + key0 + 8 * M_TOK,            &sm.Vs[buf ^ 1][w * 16 + 8][0]);
        }
        #pragma unroll
        for (int kt = 0; kt < 4; kt++) {
            short8 kf0 = *(short8*)&sm.Ks[buf][kt * 16 + l15][((g) ^ sx) * 8];
            short8 kf1 = *(short8*)&sm.Ks[buf][kt * 16 + l15][((4 + g) ^ sx) * 8];
            f32x4 e = {};
            e = __builtin_amdgcn_mfma_f32_16x16x32_bf16(qa0, kf0, e, 0, 0, 0);
            e = __builtin_amdgcn_mfma_f32_16x16x32_bf16(qa1, kf1, e, 0, 0, 0);
            #pragma unroll
            for (int r = 0; r < 4; r++) {
                float p = exp2f(e[r] * 1.44269504f);
                rsum[r] += p;
                sm.Ps[w][g * 4 + r][kt * 16 + l15] = f2bf(p);
            }
        }
        #pragma unroll
        for (int kb2 = 0; kb2 < 2; kb2++) {
            short8 pa = *(short8*)&sm.Ps[w][l15][kb2 * 32 + g * 8];
            #pragma unroll
            for (int nt = 0; nt < 4; nt++) {
                short8 vf = *(short8*)&sm.Vs[buf][nt * 16 + l15][((kb2 * 4 + g) ^ sx) * 8];
                acc[nt] = __builtin_amdgcn_mfma_f32_16x16x32_bf16(pa, vf, acc[nt], 0, 0, 0);
            }
        }
        __syncthreads();
        buf ^= 1;
    }

    #pragma unroll
    for (int r = 0; r < 4; r++) {
        float s = rsum[r];
        s += __shfl_xor(s, 1);
        s += __shfl_xor(s, 2);
        s += __shfl_xor(s, 4);
        s += __shfl_xor(s, 8);
        rsum[r] = s;
    }

    #pragma unroll
    for (int nt = 0; nt < 4; nt++)
        #pragma unroll
        for (int r = 0; r < 4; r++) {
            float y = acc[nt][r] / rsum[r];
            Yb[(size_t)(n0 + w * 16 + g * 4 + r) * DMODEL + h * DHEAD + nt * 16 + l15] = f2bf(y);
        }
}

// ---------------------------------------------------------------------------
// Mega-kernel: phase1 QKV (768 tiles / 512 blocks) | bar | phase2 attn |
// bar | phase3 out-GEMM + PE. 512 blocks x 256 threads, all co-resident.
// ---------------------------------------------------------------------------
__global__ __launch_bounds__(256) void mega_kernel(const short* xvb, const short* xtb,
                                                   const short* wqb, const short* wkb,
                                                   const short* wvb, const short* wob,
                                                   short* qb, short* kbm, short* vbt,
                                                   short* yb, float* outp,
                                                   unsigned* bar) {
    __shared__ SMemU sm;
    __shared__ float ifreq[256];
    int t = threadIdx.x;
    ifreq[t] = __expf(-(float)t * (9.210340371976184f / 512.0f));
    int bx = blockIdx.x;

    // ---- phase 1: QKV projections ----
    qkv_tile(sm.g, bx, xvb, xtb, wqb, wkb, wvb, qb, kbm, vbt);
    if (bx < 256) {
        __syncthreads();
        qkv_tile(sm.g, 512 + bx, xvb, xtb, wqb, wkb, wvb, qb, kbm, vbt);
    }
    gridbar(&bar[0], &bar[1]);

    // ---- phase 2: attention ----
    attn_tile(sm.a, bx, qb, kbm, vbt, yb);
    gridbar(&bar[0], &bar[1]);

    // ---- phase 3: output projection + positional encoding ----
    gemm_body(sm.g, yb, wob, (bx >> 3) * 64, (bx & 7) * 64,
              [&](int row, int col, float v) {
                  float x = (float)row * ifreq[col >> 1];
                  float s, c;
                  __sincosf(x, &s, &c);
                  outp[(size_t)row * DMODEL + col] = v + ((col & 1) ? c : s);
              });
}

// ---------------------------------------------------------------------------
extern "C" void kernel_launch(void* const* d_in, const int* in_sizes, int n_in,
                              void* d_out, int out_size, void* d_ws, size_t ws_size,
                              hipStream_t stream) {
    const float* xv = (const float*)d_in[0];
    const float* xt = (const float*)d_in[1];
    const float* wq = (const float*)d_in[2];
    const float* wk = (const float*)d_in[3];
    const float* wv = (const float*)d_in[4];
    const float* wo = (const float*)d_in[5];

    short* xvb = (short*)d_ws;              // 4096*512
    short* xtb = xvb + N_TOK * DMODEL;      // 1024*512
    short* wqb = xtb + M_TOK * DMODEL;      // 512*512 (B^T)
    short* wkb = wqb + DMODEL * DMODEL;
    short* wvb = wkb + DMODEL * DMODEL;
    short* wob = wvb + DMODEL * DMODEL;
    short* qb  = wob + DMODEL * DMODEL;     // 4096*512
    short* kbm = qb  + N_TOK * DMODEL;      // 1024*512
    short* vbt = kbm + M_TOK * DMODEL;      // 512*1024 (V^T)
    short* yb  = vbt + M_TOK * DMODEL;      // 4096*512
    unsigned* bar = (unsigned*)(yb + N_TOK * DMODEL);

    pack_kernel<<<1024, 256, 0, stream>>>(xv, xt, wq, wk, wv, wo,
                                          xvb, xtb, wqb, wkb, wvb, wob, bar);
    mega_kernel<<<NBLK, 256, 0, stream>>>(xvb, xtb, wqb, wkb, wvb, wob,
                                          qb, kbm, vbt, yb, (float*)d_out, bar);
}

// Round 10
// 67.077 us; speedup vs baseline: 3.1281x; 3.1281x over previous
//
#include <hip/hip_runtime.h>
#include <hip/hip_bf16.h>
#include <math.h>

#define N_TOK 4096
#define M_TOK 1024
#define DMODEL 512
#define NHEAD 8
#define DHEAD 64

typedef __attribute__((ext_vector_type(8))) short short8;
typedef __attribute__((ext_vector_type(4))) float f32x4;
typedef __attribute__((ext_vector_type(4))) float float4v;

static __device__ __forceinline__ short f2bf(float f) {
    union { float f; unsigned u; } v; v.f = f;
    unsigned r = v.u + 0x7fffu + ((v.u >> 16) & 1u);
    return (short)(r >> 16);
}

#define GLOAD_LDS16(g, l) __builtin_amdgcn_global_load_lds( \
    (const __attribute__((address_space(1))) void*)(g), \
    (__attribute__((address_space(3))) void*)(l), 16, 0, 0)

// ---------------------------------------------------------------------------
// Pack: fp32 -> bf16. Weights stored TRANSPOSED B^T[n][k].
// ---------------------------------------------------------------------------
__global__ void pack_kernel(const float* __restrict__ xv, const float* __restrict__ xt,
                            const float* __restrict__ wq, const float* __restrict__ wk,
                            const float* __restrict__ wv, const float* __restrict__ wo,
                            short* __restrict__ xvb, short* __restrict__ xtb,
                            short* __restrict__ wqb, short* __restrict__ wkb,
                            short* __restrict__ wvb, short* __restrict__ wob) {
    int idx = blockIdx.x * 256 + threadIdx.x;
    int stride = gridDim.x * 256;
    const int CXV = N_TOK * DMODEL / 8;
    const int CXT = M_TOK * DMODEL / 8;
    const int NW  = DMODEL * DMODEL;
    for (int c = idx; c < CXV; c += stride) {
        float4v f0 = *(const float4v*)&xv[c * 8];
        float4v f1 = *(const float4v*)&xv[c * 8 + 4];
        short8 o;
        #pragma unroll
        for (int j = 0; j < 4; j++) { o[j] = f2bf(f0[j]); o[j + 4] = f2bf(f1[j]); }
        *(short8*)&xvb[c * 8] = o;
    }
    for (int c = idx; c < CXT; c += stride) {
        float4v f0 = *(const float4v*)&xt[c * 8];
        float4v f1 = *(const float4v*)&xt[c * 8 + 4];
        short8 o;
        #pragma unroll
        for (int j = 0; j < 4; j++) { o[j] = f2bf(f0[j]); o[j + 4] = f2bf(f1[j]); }
        *(short8*)&xtb[c * 8] = o;
    }
    for (int i = idx; i < NW; i += stride) {
        int n = i >> 9;
        int k = i & 511;
        int h = n >> 6, e = n & 63;
        int src = h * (DMODEL * DHEAD) + k * DHEAD + e;
        wqb[i] = f2bf(wq[src]);
        wkb[i] = f2bf(wk[src]);
        wvb[i] = f2bf(wv[src]);
        wob[i] = f2bf(wo[k * DMODEL + n]);
    }
}

// ---------------------------------------------------------------------------
// GEMM body v3: 128x64 tile, BK=64, padded LDS, reg-staging with prefetch
// issued right after the barrier (r8-proven staging). 4 waves; wave w owns a
// 32x64 stripe (2x4 16x16 frags) -> ds_read:MFMA = 6:8 (vs 1:1 at 64x64).
// A: [Mrows][512] row-major. BT: [Ncols][512] row-major (pre-transposed).
// ---------------------------------------------------------------------------
template<typename EPI>
static __device__ __forceinline__ void gemm_body(const short* __restrict__ A,
                                                 const short* __restrict__ BT,
                                                 int m0, int n0, EPI epi) {
    __shared__ __align__(16) short As[128][72];   // 18 KB
    __shared__ __align__(16) short Bs[64][72];    //  9 KB
    int t = threadIdx.x;
    int lane = t & 63, w = t >> 6;
    int l15 = lane & 15, g = lane >> 4;

    int arow = t >> 1, ac0 = (t & 1) * 32;   // 2 threads/row x 32 cols
    int brow = t >> 2, bc0 = (t & 3) * 16;   // 4 threads/row x 16 cols
    const short* gA = A + (size_t)(m0 + arow) * DMODEL + ac0;
    const short* gB = BT + (size_t)(n0 + brow) * DMODEL + bc0;

    short8 ra0 = *(const short8*)gA;
    short8 ra1 = *(const short8*)(gA + 8);
    short8 ra2 = *(const short8*)(gA + 16);
    short8 ra3 = *(const short8*)(gA + 24);
    short8 rb0 = *(const short8*)gB;
    short8 rb1 = *(const short8*)(gB + 8);

    f32x4 acc[2][4] = {};
    #pragma unroll
    for (int step = 0; step < DMODEL / 64; ++step) {
        *(short8*)&As[arow][ac0]      = ra0;
        *(short8*)&As[arow][ac0 + 8]  = ra1;
        *(short8*)&As[arow][ac0 + 16] = ra2;
        *(short8*)&As[arow][ac0 + 24] = ra3;
        *(short8*)&Bs[brow][bc0]      = rb0;
        *(short8*)&Bs[brow][bc0 + 8]  = rb1;
        __syncthreads();
        if (step < DMODEL / 64 - 1) {         // issue next-step loads early
            gA += 64; gB += 64;
            ra0 = *(const short8*)gA;
            ra1 = *(const short8*)(gA + 8);
            ra2 = *(const short8*)(gA + 16);
            ra3 = *(const short8*)(gA + 24);
            rb0 = *(const short8*)gB;
            rb1 = *(const short8*)(gB + 8);
        }
        #pragma unroll
        for (int ks = 0; ks < 2; ks++) {
            short8 a[2], b[4];
            #pragma unroll
            for (int fr = 0; fr < 2; fr++)
                a[fr] = *(short8*)&As[w * 32 + fr * 16 + l15][ks * 32 + g * 8];
            #pragma unroll
            for (int fc = 0; fc < 4; fc++)
                b[fc] = *(short8*)&Bs[fc * 16 + l15][ks * 32 + g * 8];
            #pragma unroll
            for (int fr = 0; fr < 2; fr++)
                #pragma unroll
                for (int fc = 0; fc < 4; fc++)
                    acc[fr][fc] = __builtin_amdgcn_mfma_f32_16x16x32_bf16(a[fr], b[fc], acc[fr][fc], 0, 0, 0);
        }
        __syncthreads();
    }
    #pragma unroll
    for (int fr = 0; fr < 2; fr++)
        #pragma unroll
        for (int fc = 0; fc < 4; fc++)
            #pragma unroll
            for (int r = 0; r < 4; r++) {
                int orow = m0 + w * 32 + fr * 16 + g * 4 + r;
                int ocol = n0 + fc * 16 + l15;
                epi(orow, ocol, acc[fr][fc][r]);
            }
}

// ---------------------------------------------------------------------------
// Q, K, V projections in ONE launch. 384 blocks, XCD-chunk swizzle (each XCD
// gets 48 contiguous flat tiles -> A-panel reuse in its L2).
// tile<256: Q (m=tile>>3, n=tile&7); <320: K; else V (transposed out).
// ---------------------------------------------------------------------------
__global__ __launch_bounds__(256) void gemmQKV(const short* __restrict__ xvb,
                                               const short* __restrict__ xtb,
                                               const short* __restrict__ wqb,
                                               const short* __restrict__ wkb,
                                               const short* __restrict__ wvb,
                                               short* __restrict__ qb,
                                               short* __restrict__ kbm,
                                               short* __restrict__ vbt) {
    int bx = blockIdx.x;
    int tile = (bx & 7) * 48 + (bx >> 3);     // bijective: 384 = 8 * 48
    if (tile < 256) {
        gemm_body(xvb, wqb, (tile >> 3) * 128, (tile & 7) * 64,
                  [&](int row, int col, float v) { qb[(size_t)row * DMODEL + col] = f2bf(v); });
    } else if (tile < 320) {
        int b = tile - 256;
        gemm_body(xtb, wkb, (b >> 3) * 128, (b & 7) * 64,
                  [&](int row, int col, float v) { kbm[(size_t)row * DMODEL + col] = f2bf(v); });
    } else {
        int b = tile - 320;
        gemm_body(xtb, wvb, (b >> 3) * 128, (b & 7) * 64,
                  [&](int row, int col, float v) { vbt[(size_t)col * M_TOK + row] = f2bf(v); });
    }
}

// ---------------------------------------------------------------------------
// Final GEMM: out = Y * Wout(^T stored) + PE (inline sincos, LDS ifreq).
// 256 blocks, XCD-chunk swizzle (32 tiles/XCD = 4 m-tiles x 8 n-tiles).
// ---------------------------------------------------------------------------
__global__ __launch_bounds__(256) void gemmOut(const short* __restrict__ A,
                                               const short* __restrict__ BT,
                                               float* __restrict__ Cout) {
    __shared__ float ifreq[256];
    ifreq[threadIdx.x] = __expf(-(float)threadIdx.x * (9.210340371976184f / 512.0f));
    __syncthreads();
    int bx = blockIdx.x;
    int tile = (bx & 7) * 32 + (bx >> 3);     // bijective: 256 = 8 * 32
    gemm_body(A, BT, (tile >> 3) * 128, (tile & 7) * 64,
              [&](int row, int col, float v) {
                  float x = (float)row * ifreq[col >> 1];
                  float s, c;
                  __sincosf(x, &s, &c);
                  Cout[(size_t)row * DMODEL + col] = v + ((col & 1) ? c : s);
              });
}

// ---------------------------------------------------------------------------
// Attention v5 (r5/r8-proven, unchanged): LDS-staged, double-buffered,
// XOR-swizzled, block = 64 q x 1 head, no cross-wave merge.
// ---------------------------------------------------------------------------
__global__ __launch_bounds__(256) void attn_kernel(const short* __restrict__ Qb,
                                                   const short* __restrict__ Kb,
                                                   const short* __restrict__ VbT,
                                                   short* __restrict__ Yb) {
    __shared__ __align__(16) short Ks[2][64][64];
    __shared__ __align__(16) short Vs[2][64][64];
    __shared__ __align__(16) short Ps[4][16][72];

    int bid = blockIdx.x;
    int h = bid & 7;
    int n0 = (bid >> 3) * 64;
    int t = threadIdx.x;
    int lane = t & 63, w = t >> 6;
    int l15 = lane & 15, g = lane >> 4;

    const short* Kh  = Kb + h * DHEAD;
    const short* VhT = VbT + (h * DHEAD) * M_TOK;

    int srow = (lane >> 3);
    int sgran = (lane & 7) ^ srow;
    const short* gK0 = Kh + (size_t)(w * 16 + srow) * DMODEL + sgran * 8;
    const short* gV0 = VhT + (size_t)(w * 16 + srow) * M_TOK + sgran * 8;

    const short* qrow = Qb + (size_t)(n0 + w * 16 + l15) * DMODEL + h * DHEAD;
    short8 qa0 = *(const short8*)(qrow + g * 8);
    short8 qa1 = *(const short8*)(qrow + 32 + g * 8);

    f32x4 acc[4] = {};
    f32x4 rsum = {};
    int sx = l15 & 7;

    GLOAD_LDS16(gK0,              &Ks[0][w * 16][0]);
    GLOAD_LDS16(gK0 + 8 * DMODEL, &Ks[0][w * 16 + 8][0]);
    GLOAD_LDS16(gV0,              &Vs[0][w * 16][0]);
    GLOAD_LDS16(gV0 + 8 * M_TOK,  &Vs[0][w * 16 + 8][0]);
    __syncthreads();

    int buf = 0;
    for (int it = 0; it < 16; ++it) {
        if (it < 15) {
            int key0 = (it + 1) * 64;
            GLOAD_LDS16(gK0 + (size_t)key0 * DMODEL,       &Ks[buf ^ 1][w * 16][0]);
            GLOAD_LDS16(gK0 + (size_t)(key0 + 8) * DMODEL, &Ks[buf ^ 1][w * 16 + 8][0]);
            GLOAD_LDS16(gV0 + key0,                        &Vs[buf ^ 1][w * 16][0]);
            GLOAD_LDS16(gV0 + key0 + 8 * M_TOK,            &Vs[buf ^ 1][w * 16 + 8][0]);
        }
        #pragma unroll
        for (int kt = 0; kt < 4; kt++) {
            short8 kf0 = *(short8*)&Ks[buf][kt * 16 + l15][((g) ^ sx) * 8];
            short8 kf1 = *(short8*)&Ks[buf][kt * 16 + l15][((4 + g) ^ sx) * 8];
            f32x4 e = {};
            e = __builtin_amdgcn_mfma_f32_16x16x32_bf16(qa0, kf0, e, 0, 0, 0);
            e = __builtin_amdgcn_mfma_f32_16x16x32_bf16(qa1, kf1, e, 0, 0, 0);
            #pragma unroll
            for (int r = 0; r < 4; r++) {
                float p = exp2f(e[r] * 1.44269504f);
                rsum[r] += p;
                Ps[w][g * 4 + r][kt * 16 + l15] = f2bf(p);
            }
        }
        #pragma unroll
        for (int kb2 = 0; kb2 < 2; kb2++) {
            short8 pa = *(short8*)&Ps[w][l15][kb2 * 32 + g * 8];
            #pragma unroll
            for (int nt = 0; nt < 4; nt++) {
                short8 vf = *(short8*)&Vs[buf][nt * 16 + l15][((kb2 * 4 + g) ^ sx) * 8];
                acc[nt] = __builtin_amdgcn_mfma_f32_16x16x32_bf16(pa, vf, acc[nt], 0, 0, 0);
            }
        }
        __syncthreads();
        buf ^= 1;
    }

    #pragma unroll
    for (int r = 0; r < 4; r++) {
        float s = rsum[r];
        s += __shfl_xor(s, 1);
        s += __shfl_xor(s, 2);
        s += __shfl_xor(s, 4);
        s += __shfl_xor(s, 8);
        rsum[r] = s;
    }

    #pragma unroll
    for (int nt = 0; nt < 4; nt++)
        #pragma unroll
        for (int r = 0; r < 4; r++) {
            float y = acc[nt][r] / rsum[r];
            Yb[(size_t)(n0 + w * 16 + g * 4 + r) * DMODEL + h * DHEAD + nt * 16 + l15] = f2bf(y);
        }
}

// ---------------------------------------------------------------------------
extern "C" void kernel_launch(void* const* d_in, const int* in_sizes, int n_in,
                              void* d_out, int out_size, void* d_ws, size_t ws_size,
                              hipStream_t stream) {
    const float* xv = (const float*)d_in[0];
    const float* xt = (const float*)d_in[1];
    const float* wq = (const float*)d_in[2];
    const float* wk = (const float*)d_in[3];
    const float* wv = (const float*)d_in[4];
    const float* wo = (const float*)d_in[5];

    short* xvb = (short*)d_ws;              // 4096*512
    short* xtb = xvb + N_TOK * DMODEL;      // 1024*512
    short* wqb = xtb + M_TOK * DMODEL;      // 512*512 (B^T)
    short* wkb = wqb + DMODEL * DMODEL;
    short* wvb = wkb + DMODEL * DMODEL;
    short* wob = wvb + DMODEL * DMODEL;
    short* qb  = wob + DMODEL * DMODEL;     // 4096*512
    short* kbm = qb  + N_TOK * DMODEL;      // 1024*512
    short* vbt = kbm + M_TOK * DMODEL;      // 512*1024 (V^T)
    short* yb  = vbt + M_TOK * DMODEL;      // 4096*512

    pack_kernel<<<2048, 256, 0, stream>>>(xv, xt, wq, wk, wv, wo,
                                          xvb, xtb, wqb, wkb, wvb, wob);
    gemmQKV<<<384, 256, 0, stream>>>(xvb, xtb, wqb, wkb, wvb, qb, kbm, vbt);
    attn_kernel<<<512, 256, 0, stream>>>(qb, kbm, vbt, yb);
    gemmOut<<<256, 256, 0, stream>>>(yb, wob, (float*)d_out);
}

// Round 11
// 58.450 us; speedup vs baseline: 3.5898x; 1.1476x over previous
//
#include <hip/hip_runtime.h>
#include <hip/hip_bf16.h>
#include <math.h>

#define N_TOK 4096
#define M_TOK 1024
#define DMODEL 512
#define NHEAD 8
#define DHEAD 64

typedef __attribute__((ext_vector_type(8))) short short8;
typedef __attribute__((ext_vector_type(4))) float f32x4;
typedef __attribute__((ext_vector_type(4))) float float4v;

static __device__ __forceinline__ short f2bf(float f) {
    union { float f; unsigned u; } v; v.f = f;
    unsigned r = v.u + 0x7fffu + ((v.u >> 16) & 1u);
    return (short)(r >> 16);
}

#define GLOAD_LDS16(g, l) __builtin_amdgcn_global_load_lds( \
    (const __attribute__((address_space(1))) void*)(g), \
    (__attribute__((address_space(3))) void*)(l), 16, 0, 0)

// ---------------------------------------------------------------------------
// Pack v2. Blocks [0,192): wq/wk/wv head-tile transposes via LDS (coalesced
// both sides). Blocks [192,256): wo tile transposes. Blocks [256+): xv/xt
// bf16 conversion, grid-stride.
//   wq/wk/wv: B^T[n=h*64+e][k=d] = W[h][d][e]   (per head: 512x64 -> 64x512)
//   wo:       B^T[n=j][k=d]      = Wout[d][j]
// ---------------------------------------------------------------------------
__global__ __launch_bounds__(256) void pack_kernel(
        const float* __restrict__ xv, const float* __restrict__ xt,
        const float* __restrict__ wq, const float* __restrict__ wk,
        const float* __restrict__ wv, const float* __restrict__ wo,
        short* __restrict__ xvb, short* __restrict__ xtb,
        short* __restrict__ wqb, short* __restrict__ wkb,
        short* __restrict__ wvb, short* __restrict__ wob) {
    int bid = blockIdx.x;
    int t = threadIdx.x;
    if (bid < 256) {
        __shared__ float lds[64][65];
        const float* src;
        short* dst;
        int srstride;   // source row stride (floats)
        int dr0, dc0;   // dst base row/col
        if (bid < 192) {
            int mat = bid >> 6;          // 0..2 -> wq/wk/wv
            int hb = bid & 63;
            int h = hb >> 3, dt = hb & 7;
            const float* W = (mat == 0) ? wq : (mat == 1) ? wk : wv;
            src = W + (size_t)h * (DMODEL * DHEAD) + (size_t)(dt * 64) * DHEAD;
            srstride = DHEAD;            // contiguous 16KB chunk
            dst = (mat == 0) ? wqb : (mat == 1) ? wkb : wvb;
            dr0 = h * 64;                // n = h*64 + e
            dc0 = dt * 64;               // k = d
        } else {
            int b = bid - 192;
            int rt = b >> 3, ct = b & 7;
            src = wo + (size_t)(rt * 64) * DMODEL + ct * 64;
            srstride = DMODEL;
            dst = wob;
            dr0 = ct * 64;               // n = j
            dc0 = rt * 64;               // k = d
        }
        {
            int r = t >> 2, c0 = (t & 3) * 16;
            const float* s = src + (size_t)r * srstride + c0;
            #pragma unroll
            for (int j = 0; j < 4; j++) {
                float4v v = *(const float4v*)(s + j * 4);
                lds[r][c0 + j * 4 + 0] = v[0];
                lds[r][c0 + j * 4 + 1] = v[1];
                lds[r][c0 + j * 4 + 2] = v[2];
                lds[r][c0 + j * 4 + 3] = v[3];
            }
        }
        __syncthreads();
        {
            int outr = t >> 2, c0 = (t & 3) * 16;   // out row = e (or j)
            short8 o0, o1;
            #pragma unroll
            for (int j = 0; j < 8; j++) {
                o0[j] = f2bf(lds[c0 + j][outr]);
                o1[j] = f2bf(lds[c0 + 8 + j][outr]);
            }
            short* d = dst + (size_t)(dr0 + outr) * DMODEL + dc0 + c0;
            *(short8*)d = o0;
            *(short8*)(d + 8) = o1;
        }
        return;
    }
    // activations
    int idx = (bid - 256) * 256 + t;
    int stride = (gridDim.x - 256) * 256;
    const int CXV = N_TOK * DMODEL / 8;
    const int CXT = M_TOK * DMODEL / 8;
    for (int c = idx; c < CXV; c += stride) {
        float4v f0 = *(const float4v*)&xv[c * 8];
        float4v f1 = *(const float4v*)&xv[c * 8 + 4];
        short8 o;
        #pragma unroll
        for (int j = 0; j < 4; j++) { o[j] = f2bf(f0[j]); o[j + 4] = f2bf(f1[j]); }
        *(short8*)&xvb[c * 8] = o;
    }
    for (int c = idx; c < CXT; c += stride) {
        float4v f0 = *(const float4v*)&xt[c * 8];
        float4v f1 = *(const float4v*)&xt[c * 8 + 4];
        short8 o;
        #pragma unroll
        for (int j = 0; j < 4; j++) { o[j] = f2bf(f0[j]); o[j + 4] = f2bf(f1[j]); }
        *(short8*)&xtb[c * 8] = o;
    }
}

// ---------------------------------------------------------------------------
// GEMM body (r5/r8-proven): 64x64, BK=64, padded LDS, reg-staging with
// next-step loads issued right after the barrier. Wave (wr,wc) = 32x32 quad.
// ---------------------------------------------------------------------------
template<typename EPI>
static __device__ __forceinline__ void gemm_body(const short* __restrict__ A,
                                                 const short* __restrict__ BT,
                                                 int m0, int n0, EPI epi) {
    __shared__ __align__(16) short As[64][72];
    __shared__ __align__(16) short Bs[64][72];
    int t = threadIdx.x;
    int lane = t & 63, w = t >> 6;
    int wr = w >> 1, wc = w & 1;
    int l15 = lane & 15, g = lane >> 4;

    int row = t >> 2, c0 = (t & 3) * 16;
    const short* gA = A + (size_t)(m0 + row) * DMODEL + c0;
    const short* gB = BT + (size_t)(n0 + row) * DMODEL + c0;

    short8 ra0 = *(const short8*)gA;
    short8 ra1 = *(const short8*)(gA + 8);
    short8 rb0 = *(const short8*)gB;
    short8 rb1 = *(const short8*)(gB + 8);

    f32x4 acc[2][2] = {};
    #pragma unroll
    for (int step = 0; step < DMODEL / 64; ++step) {
        *(short8*)&As[row][c0]     = ra0;
        *(short8*)&As[row][c0 + 8] = ra1;
        *(short8*)&Bs[row][c0]     = rb0;
        *(short8*)&Bs[row][c0 + 8] = rb1;
        __syncthreads();
        if (step < DMODEL / 64 - 1) {
            gA += 64; gB += 64;
            ra0 = *(const short8*)gA;
            ra1 = *(const short8*)(gA + 8);
            rb0 = *(const short8*)gB;
            rb1 = *(const short8*)(gB + 8);
        }
        #pragma unroll
        for (int ks = 0; ks < 2; ks++) {
            short8 a[2], b[2];
            #pragma unroll
            for (int fr = 0; fr < 2; fr++) a[fr] = *(short8*)&As[wr * 32 + fr * 16 + l15][ks * 32 + g * 8];
            #pragma unroll
            for (int fc = 0; fc < 2; fc++) b[fc] = *(short8*)&Bs[wc * 32 + fc * 16 + l15][ks * 32 + g * 8];
            #pragma unroll
            for (int fr = 0; fr < 2; fr++)
                #pragma unroll
                for (int fc = 0; fc < 2; fc++)
                    acc[fr][fc] = __builtin_amdgcn_mfma_f32_16x16x32_bf16(a[fr], b[fc], acc[fr][fc], 0, 0, 0);
        }
        __syncthreads();
    }
    #pragma unroll
    for (int fr = 0; fr < 2; fr++)
        #pragma unroll
        for (int fc = 0; fc < 2; fc++)
            #pragma unroll
            for (int r = 0; r < 4; r++) {
                int orow = m0 + wr * 32 + fr * 16 + g * 4 + r;
                int ocol = n0 + wc * 32 + fc * 16 + l15;
                epi(orow, ocol, acc[fr][fc][r]);
            }
}

// ---------------------------------------------------------------------------
// Q, K, V projections in ONE launch. grid (96, 8):
//   bx<64: Q;  bx<80: K;  else: V (transposed out V^T[d][1024])
// ---------------------------------------------------------------------------
__global__ __launch_bounds__(256) void gemmQKV(const short* __restrict__ xvb,
                                               const short* __restrict__ xtb,
                                               const short* __restrict__ wqb,
                                               const short* __restrict__ wkb,
                                               const short* __restrict__ wvb,
                                               short* __restrict__ qb,
                                               short* __restrict__ kbm,
                                               short* __restrict__ vbt) {
    int bx = blockIdx.x;
    int n0 = blockIdx.y * 64;
    if (bx < 64) {
        short* C = qb;
        gemm_body(xvb, wqb, bx * 64, n0,
                  [&](int row, int col, float v) { C[(size_t)row * DMODEL + col] = f2bf(v); });
    } else if (bx < 80) {
        short* C = kbm;
        gemm_body(xtb, wkb, (bx - 64) * 64, n0,
                  [&](int row, int col, float v) { C[(size_t)row * DMODEL + col] = f2bf(v); });
    } else {
        short* C = vbt;
        gemm_body(xtb, wvb, (bx - 80) * 64, n0,
                  [&](int row, int col, float v) { C[(size_t)col * M_TOK + row] = f2bf(v); });
    }
}

// ---------------------------------------------------------------------------
// Final GEMM: out = Y * Wout(^T stored) + PE (inline sincos, LDS ifreq).
// ---------------------------------------------------------------------------
__global__ __launch_bounds__(256) void gemmOut(const short* __restrict__ A,
                                               const short* __restrict__ BT,
                                               float* __restrict__ Cout) {
    __shared__ float ifreq[256];
    ifreq[threadIdx.x] = __expf(-(float)threadIdx.x * (9.210340371976184f / 512.0f));
    __syncthreads();
    gemm_body(A, BT, blockIdx.x * 64, blockIdx.y * 64,
              [&](int row, int col, float v) {
                  float x = (float)row * ifreq[col >> 1];
                  float s, c;
                  __sincosf(x, &s, &c);
                  Cout[(size_t)row * DMODEL + col] = v + ((col & 1) ? c : s);
              });
}

// ---------------------------------------------------------------------------
// Attention v5 (r5-proven, unchanged): LDS-staged, double-buffered,
// XOR-swizzled, block = 64 q x 1 head, no cross-wave merge.
// ---------------------------------------------------------------------------
__global__ __launch_bounds__(256) void attn_kernel(const short* __restrict__ Qb,
                                                   const short* __restrict__ Kb,
                                                   const short* __restrict__ VbT,
                                                   short* __restrict__ Yb) {
    __shared__ __align__(16) short Ks[2][64][64];
    __shared__ __align__(16) short Vs[2][64][64];
    __shared__ __align__(16) short Ps[4][16][72];

    int bid = blockIdx.x;
    int h = bid & 7;
    int n0 = (bid >> 3) * 64;
    int t = threadIdx.x;
    int lane = t & 63, w = t >> 6;
    int l15 = lane & 15, g = lane >> 4;

    const short* Kh  = Kb + h * DHEAD;
    const short* VhT = VbT + (h * DHEAD) * M_TOK;

    int srow = (lane >> 3);
    int sgran = (lane & 7) ^ srow;
    const short* gK0 = Kh + (size_t)(w * 16 + srow) * DMODEL + sgran * 8;
    const short* gV0 = VhT + (size_t)(w * 16 + srow) * M_TOK + sgran * 8;

    const short* qrow = Qb + (size_t)(n0 + w * 16 + l15) * DMODEL + h * DHEAD;
    short8 qa0 = *(const short8*)(qrow + g * 8);
    short8 qa1 = *(const short8*)(qrow + 32 + g * 8);

    f32x4 acc[4] = {};
    f32x4 rsum = {};
    int sx = l15 & 7;

    GLOAD_LDS16(gK0,              &Ks[0][w * 16][0]);
    GLOAD_LDS16(gK0 + 8 * DMODEL, &Ks[0][w * 16 + 8][0]);
    GLOAD_LDS16(gV0,              &Vs[0][w * 16][0]);
    GLOAD_LDS16(gV0 + 8 * M_TOK,  &Vs[0][w * 16 + 8][0]);
    __syncthreads();

    int buf = 0;
    for (int it = 0; it < 16; ++it) {
        if (it < 15) {
            int key0 = (it + 1) * 64;
            GLOAD_LDS16(gK0 + (size_t)key0 * DMODEL,       &Ks[buf ^ 1][w * 16][0]);
            GLOAD_LDS16(gK0 + (size_t)(key0 + 8) * DMODEL, &Ks[buf ^ 1][w * 16 + 8][0]);
            GLOAD_LDS16(gV0 + key0,                        &Vs[buf ^ 1][w * 16][0]);
            GLOAD_LDS16(gV0 + key0 + 8 * M_TOK,            &Vs[buf ^ 1][w * 16 + 8][0]);
        }
        #pragma unroll
        for (int kt = 0; kt < 4; kt++) {
            short8 kf0 = *(short8*)&Ks[buf][kt * 16 + l15][((g) ^ sx) * 8];
            short8 kf1 = *(short8*)&Ks[buf][kt * 16 + l15][((4 + g) ^ sx) * 8];
            f32x4 e = {};
            e = __builtin_amdgcn_mfma_f32_16x16x32_bf16(qa0, kf0, e, 0, 0, 0);
            e = __builtin_amdgcn_mfma_f32_16x16x32_bf16(qa1, kf1, e, 0, 0, 0);
            #pragma unroll
            for (int r = 0; r < 4; r++) {
                float p = exp2f(e[r] * 1.44269504f);
                rsum[r] += p;
                Ps[w][g * 4 + r][kt * 16 + l15] = f2bf(p);
            }
        }
        #pragma unroll
        for (int kb2 = 0; kb2 < 2; kb2++) {
            short8 pa = *(short8*)&Ps[w][l15][kb2 * 32 + g * 8];
            #pragma unroll
            for (int nt = 0; nt < 4; nt++) {
                short8 vf = *(short8*)&Vs[buf][nt * 16 + l15][((kb2 * 4 + g) ^ sx) * 8];
                acc[nt] = __builtin_amdgcn_mfma_f32_16x16x32_bf16(pa, vf, acc[nt], 0, 0, 0);
            }
        }
        __syncthreads();
        buf ^= 1;
    }

    #pragma unroll
    for (int r = 0; r < 4; r++) {
        float s = rsum[r];
        s += __shfl_xor(s, 1);
        s += __shfl_xor(s, 2);
        s += __shfl_xor(s, 4);
        s += __shfl_xor(s, 8);
        rsum[r] = s;
    }

    #pragma unroll
    for (int nt = 0; nt < 4; nt++)
        #pragma unroll
        for (int r = 0; r < 4; r++) {
            float y = acc[nt][r] / rsum[r];
            Yb[(size_t)(n0 + w * 16 + g * 4 + r) * DMODEL + h * DHEAD + nt * 16 + l15] = f2bf(y);
        }
}

// ---------------------------------------------------------------------------
extern "C" void kernel_launch(void* const* d_in, const int* in_sizes, int n_in,
                              void* d_out, int out_size, void* d_ws, size_t ws_size,
                              hipStream_t stream) {
    const float* xv = (const float*)d_in[0];
    const float* xt = (const float*)d_in[1];
    const float* wq = (const float*)d_in[2];
    const float* wk = (const float*)d_in[3];
    const float* wv = (const float*)d_in[4];
    const float* wo = (const float*)d_in[5];

    short* xvb = (short*)d_ws;              // 4096*512
    short* xtb = xvb + N_TOK * DMODEL;      // 1024*512
    short* wqb = xtb + M_TOK * DMODEL;      // 512*512 (B^T)
    short* wkb = wqb + DMODEL * DMODEL;
    short* wvb = wkb + DMODEL * DMODEL;
    short* wob = wvb + DMODEL * DMODEL;
    short* qb  = wob + DMODEL * DMODEL;     // 4096*512
    short* kbm = qb  + N_TOK * DMODEL;      // 1024*512
    short* vbt = kbm + M_TOK * DMODEL;      // 512*1024 (V^T)
    short* yb  = vbt + M_TOK * DMODEL;      // 4096*512

    pack_kernel<<<1280, 256, 0, stream>>>(xv, xt, wq, wk, wv, wo,
                                          xvb, xtb, wqb, wkb, wvb, wob);
    gemmQKV<<<dim3(96, 8), 256, 0, stream>>>(xvb, xtb, wqb, wkb, wvb, qb, kbm, vbt);
    attn_kernel<<<512, 256, 0, stream>>>(qb, kbm, vbt, yb);
    gemmOut<<<dim3(64, 8), 256, 0, stream>>>(yb, wob, (float*)d_out);
}